// Round 1
// baseline (731.015 us; speedup 1.0000x reference)
//
#include <hip/hip_runtime.h>
#include <math.h>

#define NN 100000      // nodes
#define NE 3200000     // edges
#define INF 512        // in feat
#define HID 32         // hidden
#define NC 7           // classes

// ---------------- dtype detection: int64 (flag=1) vs int32 (flag=0) ----------------
__global__ void k_detect(const unsigned* __restrict__ edges, int* __restrict__ flag){
    __shared__ int nz;
    if (threadIdx.x == 0) nz = 0;
    __syncthreads();
    // if int64 with values < 2^31, every odd 32-bit word is 0
    if (edges[2*threadIdx.x + 1] != 0u) atomicOr(&nz, 1);
    __syncthreads();
    if (threadIdx.x == 0) *flag = (nz == 0) ? 1 : 0;
}

// ---------------- convert to int32 + in-degree histogram ----------------
__global__ __launch_bounds__(256) void k_convert_hist(const void* __restrict__ edges, const int* __restrict__ flag,
                                                      int* __restrict__ src32, int* __restrict__ dst32,
                                                      int* __restrict__ cnt){
    int e = blockIdx.x*256 + threadIdx.x;
    if (e >= NE) return;
    int s, d;
    if (*flag){
        const long long* p = (const long long*)edges;
        s = (int)p[e]; d = (int)p[NE + e];
    } else {
        const int* p = (const int*)edges;
        s = p[e]; d = p[NE + e];
    }
    src32[e] = s; dst32[e] = d;
    atomicAdd(&cnt[d], 1);
}

// ---------------- scan (3-pass) ----------------
__global__ __launch_bounds__(256) void k_scan1(const int* __restrict__ cnt, int* __restrict__ bsum){
    __shared__ int sd[256];
    int idx = blockIdx.x*256 + threadIdx.x;
    sd[threadIdx.x] = (idx < NN) ? cnt[idx] : 0;
    __syncthreads();
    for (int s = 128; s > 0; s >>= 1){
        if (threadIdx.x < s) sd[threadIdx.x] += sd[threadIdx.x + s];
        __syncthreads();
    }
    if (threadIdx.x == 0) bsum[blockIdx.x] = sd[0];
}

__global__ __launch_bounds__(512) void k_scan2(int* __restrict__ bsum, int nb){
    __shared__ int sd[512];
    int t = threadIdx.x;
    int v = (t < nb) ? bsum[t] : 0;
    sd[t] = v;
    __syncthreads();
    for (int off = 1; off < 512; off <<= 1){
        int add = (t >= off) ? sd[t - off] : 0;
        __syncthreads();
        sd[t] += add;
        __syncthreads();
    }
    if (t < nb) bsum[t] = sd[t] - v;   // exclusive
}

__global__ __launch_bounds__(256) void k_scan3(const int* __restrict__ cnt, const int* __restrict__ bsum,
                                               int* __restrict__ row_ptr, int* __restrict__ cursor,
                                               float* __restrict__ dinv){
    __shared__ int sd[256];
    int t = threadIdx.x, idx = blockIdx.x*256 + t;
    int c = (idx < NN) ? cnt[idx] : 0;
    sd[t] = c;
    __syncthreads();
    for (int off = 1; off < 256; off <<= 1){
        int add = (t >= off) ? sd[t - off] : 0;
        __syncthreads();
        sd[t] += add;
        __syncthreads();
    }
    int ex = bsum[blockIdx.x] + sd[t] - c;
    if (idx < NN){
        row_ptr[idx] = ex;
        cursor[idx]  = ex;
        dinv[idx]    = rsqrtf((float)(c + 1));   // +1 self-loop; deg >= 1 always
        if (idx == NN - 1) row_ptr[NN] = ex + c;
    }
}

// ---------------- CSR fill (counting sort by dst) ----------------
__global__ __launch_bounds__(256) void k_fill(const int* __restrict__ src32, const int* __restrict__ dst32,
                                              int* __restrict__ cursor, int* __restrict__ csr_src){
    int e = blockIdx.x*256 + threadIdx.x;
    if (e >= NE) return;
    int p = atomicAdd(&cursor[dst32[e]], 1);
    csr_src[p] = src32[e];
}

// ---------------- GEMM1: h1s = (x @ W1) * dinv[row], [NN][32] ----------------
__global__ __launch_bounds__(256) void k_gemm1(const float* __restrict__ x, const float* __restrict__ W1,
                                               const float* __restrict__ dinv, float* __restrict__ h1s){
    __shared__ float xt[256][33];   // +1 pad: bank-conflict-free row reads
    __shared__ float wt[32][32];    // k uniform in wave -> broadcast reads
    const int tid = threadIdx.x;
    const int row0 = blockIdx.x * 256;
    const int cg = tid & 7;    // col group: cols cg*4 .. cg*4+3
    const int rg = tid >> 3;   // row group: rows rg*8 .. rg*8+7
    float acc[8][4];
    #pragma unroll
    for (int i = 0; i < 8; ++i){ acc[i][0]=0.f; acc[i][1]=0.f; acc[i][2]=0.f; acc[i][3]=0.f; }

    for (int k0 = 0; k0 < INF; k0 += 32){
        { // W tile 32x32
            int kk = tid >> 3, c4 = (tid & 7) * 4;
            *(float4*)&wt[kk][c4] = *(const float4*)&W1[(k0 + kk)*HID + c4];
        }
        #pragma unroll
        for (int l = 0; l < 8; ++l){ // x tile 256x32, coalesced float4 loads
            int idx4 = l*256 + tid;
            int r = idx4 >> 3, c4 = idx4 & 7;
            int grow = row0 + r;
            float4 v = make_float4(0.f, 0.f, 0.f, 0.f);
            if (grow < NN) v = *(const float4*)&x[(size_t)grow*INF + k0 + c4*4];
            float* dst = &xt[r][c4*4];
            dst[0]=v.x; dst[1]=v.y; dst[2]=v.z; dst[3]=v.w;
        }
        __syncthreads();
        for (int k = 0; k < 32; ++k){
            float4 w = *(const float4*)&wt[k][cg*4];
            #pragma unroll
            for (int i = 0; i < 8; ++i){
                float xv = xt[rg*8 + i][k];
                acc[i][0] = fmaf(xv, w.x, acc[i][0]);
                acc[i][1] = fmaf(xv, w.y, acc[i][1]);
                acc[i][2] = fmaf(xv, w.z, acc[i][2]);
                acc[i][3] = fmaf(xv, w.w, acc[i][3]);
            }
        }
        __syncthreads();
    }
    #pragma unroll
    for (int i = 0; i < 8; ++i){
        int r = row0 + rg*8 + i;
        if (r < NN){
            float d = dinv[r];
            float4 o; o.x=acc[i][0]*d; o.y=acc[i][1]*d; o.z=acc[i][2]*d; o.w=acc[i][3]*d;
            *(float4*)&h1s[(size_t)r*HID + cg*4] = o;
        }
    }
}

// ---------------- Aggregation 1 + bias + ReLU: 32 lanes per node ----------------
__global__ __launch_bounds__(256) void k_agg1(const float* __restrict__ h1s, const int* __restrict__ row_ptr,
                                              const int* __restrict__ csr_src, const float* __restrict__ dinv,
                                              const float* __restrict__ b1, float* __restrict__ relu1){
    int lane = threadIdx.x & 31;
    int v = blockIdx.x*8 + (threadIdx.x >> 5);
    if (v >= NN) return;
    float acc = h1s[(size_t)v*HID + lane];      // self-loop term (h1s already has dinv[src])
    int beg = row_ptr[v], end = row_ptr[v+1];
    for (int e = beg; e < end; ++e){
        int s = csr_src[e];
        acc += h1s[(size_t)s*HID + lane];       // coalesced 128B gather across the 32-lane group
    }
    float r = dinv[v]*acc + b1[lane];
    relu1[(size_t)v*HID + lane] = fmaxf(r, 0.f);
}

// ---------------- pad W2 [32][7] -> [32][8] ----------------
__global__ void k_padW2(const float* __restrict__ W2, float* __restrict__ w2p){
    int t = threadIdx.x;            // 256 == 32*8
    int k = t >> 3, j = t & 7;
    w2p[t] = (j < NC) ? W2[k*NC + j] : 0.f;
}

// ---------------- GEMM2: h2s = (relu1 @ W2pad) * dinv[row], [NN][8] ----------------
__global__ __launch_bounds__(256) void k_gemm2(const float* __restrict__ relu1, const float* __restrict__ w2p,
                                               const float* __restrict__ dinv, float* __restrict__ h2s){
    __shared__ float w2s[256];
    w2s[threadIdx.x] = w2p[threadIdx.x];
    __syncthreads();
    int r = blockIdx.x*256 + threadIdx.x;
    if (r >= NN) return;
    float rv[HID];
    #pragma unroll
    for (int q = 0; q < 8; ++q){
        float4 t = *(const float4*)&relu1[(size_t)r*HID + q*4];
        rv[q*4]=t.x; rv[q*4+1]=t.y; rv[q*4+2]=t.z; rv[q*4+3]=t.w;
    }
    float acc[8] = {0.f,0.f,0.f,0.f,0.f,0.f,0.f,0.f};
    #pragma unroll
    for (int k = 0; k < HID; ++k){
        #pragma unroll
        for (int j = 0; j < 8; ++j) acc[j] = fmaf(rv[k], w2s[k*8 + j], acc[j]);
    }
    float d = dinv[r];
    float4 o0; o0.x=acc[0]*d; o0.y=acc[1]*d; o0.z=acc[2]*d; o0.w=acc[3]*d;
    float4 o1; o1.x=acc[4]*d; o1.y=acc[5]*d; o1.z=acc[6]*d; o1.w=acc[7]*d;
    *(float4*)&h2s[(size_t)r*8]     = o0;
    *(float4*)&h2s[(size_t)r*8 + 4] = o1;
}

// ---------------- Aggregation 2 + bias + softmax: 8 lanes per node ----------------
__global__ __launch_bounds__(256) void k_agg2(const float* __restrict__ h2s, const int* __restrict__ row_ptr,
                                              const int* __restrict__ csr_src, const float* __restrict__ dinv,
                                              const float* __restrict__ b2, float* __restrict__ out){
    int j = threadIdx.x & 7;
    int v = blockIdx.x*32 + (threadIdx.x >> 3);
    if (v >= NN) return;
    float acc = h2s[(size_t)v*8 + j];           // self (col 7 is 0 by construction)
    int beg = row_ptr[v], end = row_ptr[v+1];
    for (int e = beg; e < end; ++e){
        acc += h2s[(size_t)csr_src[e]*8 + j];
    }
    float logit = (j < NC) ? (dinv[v]*acc + b2[j]) : -INFINITY;
    float m = logit;
    #pragma unroll
    for (int off = 1; off < 8; off <<= 1) m = fmaxf(m, __shfl_xor(m, off, 8));
    float ex = __expf(logit - m);               // j==7: exp(-inf)=0
    float s = ex;
    #pragma unroll
    for (int off = 1; off < 8; off <<= 1) s += __shfl_xor(s, off, 8);
    if (j < NC) out[(size_t)v*NC + j] = ex / s;
}

extern "C" void kernel_launch(void* const* d_in, const int* in_sizes, int n_in,
                              void* d_out, int out_size, void* d_ws, size_t ws_size,
                              hipStream_t stream){
    const float* x  = (const float*)d_in[0];
    const void*  ei = d_in[1];
    const float* W1 = (const float*)d_in[2];
    const float* b1 = (const float*)d_in[3];
    const float* W2 = (const float*)d_in[4];
    const float* b2 = (const float*)d_in[5];
    float* out = (float*)d_out;

    char* ws = (char*)d_ws;
    size_t off = 0;
    auto alloc = [&](size_t bytes)->char*{
        char* p = ws + off; off += (bytes + 255) & ~(size_t)255; return p;
    };
    int*   src32  = (int*)  alloc((size_t)NE*4);
    int*   dst32  = (int*)  alloc((size_t)NE*4);
    int*   csr    = (int*)  alloc((size_t)NE*4);
    int*   cnt    = (int*)  alloc((size_t)NN*4);
    int*   rowp   = (int*)  alloc((size_t)(NN+1)*4);
    int*   cursor = (int*)  alloc((size_t)NN*4);
    int*   bsum   = (int*)  alloc(512*4);
    int*   flag   = (int*)  alloc(4);
    float* dinv   = (float*)alloc((size_t)NN*4);
    float* h1s    = (float*)alloc((size_t)NN*HID*4);
    float* relu1  = (float*)alloc((size_t)NN*HID*4);
    float* h2s    = (float*)alloc((size_t)NN*8*4);
    float* w2p    = (float*)alloc(256*4);

    const int EB = (NE + 255)/256;   // 12500
    const int NB = (NN + 255)/256;   // 391

    hipMemsetAsync(cnt, 0, (size_t)NN*4, stream);
    k_detect<<<1, 256, 0, stream>>>((const unsigned*)ei, flag);
    k_convert_hist<<<EB, 256, 0, stream>>>(ei, flag, src32, dst32, cnt);
    k_scan1<<<NB, 256, 0, stream>>>(cnt, bsum);
    k_scan2<<<1, 512, 0, stream>>>(bsum, NB);
    k_scan3<<<NB, 256, 0, stream>>>(cnt, bsum, rowp, cursor, dinv);
    k_fill<<<EB, 256, 0, stream>>>(src32, dst32, cursor, csr);
    k_gemm1<<<NB, 256, 0, stream>>>(x, W1, dinv, h1s);
    k_agg1<<<NN/8, 256, 0, stream>>>(h1s, rowp, csr, dinv, b1, relu1);
    k_padW2<<<1, 256, 0, stream>>>(W2, w2p);
    k_gemm2<<<NB, 256, 0, stream>>>(relu1, w2p, dinv, h2s);
    k_agg2<<<NN/32, 256, 0, stream>>>(h2s, rowp, csr, dinv, b2, out);
}